// Round 5
// baseline (177.679 us; speedup 1.0000x reference)
//
#include <hip/hip_runtime.h>

// NeurTWs R15: structural register halving so 4 waves/SIMD fit WITHOUT
// spill. Evidence R10-R14: waves convert to BW (3 waves = 2.4-3.0 TB/s,
// 4 waves = 3.3-3.5 TB/s even while spilling); body needs ~148 regs so
// every launch_bounds(256,4) attempt so far spilled ~16+ regs (WRITE
// 11 -> 69..81 MB) and lost the gain. R14 (index/enc prefetch, 3 waves)
// = 59us ~= R10: loop-head latency was NOT the critical path -> execute
// the pre-committed restructure:
//   Split row-tiles into two sequential halves: do rt{0,1} COMPLETELY
//   (feat ktiles -> pe ktile -> GEMM4 -> store), then rt{2,3}.
//   - acc[4][4] 64 AGPR -> acc[2][4] 32, reused across halves
//   - fA 32 VGPR -> 16 (half-B gathers issued after half-A consumed,
//     covered by pe-ktile + GEMM4 + 4-wave TLP)
//   - GEMM2 streamed per-rt: a_h 16->8, pc 32->8. Safe because each rt's
//     h-tile (rows r0+rt*16..+16, all 32 cols) is fully consumed by that
//     rt's A-fragment read before the pe write clobbers those same rows
//     (wave-private in-order DS, validated since R6/R9).
//   Peak ~118 regs <= 128 -> (256,4) clean, grid 1024 = 4 blocks/CU,
//   zero tail (1M rows = 1024 x 256 x 4 exactly). Cost: 12 extra
//   ds_read_b128/iter (b0/bk re-reads) ~ 150cy -- noise.
// Keep R14's cross-iter ndr/kk/enc prefetch (9 regs).
// DECISIVE COUNTER: WRITE_SIZE ~11-20 MB = no spill; >>30 MB = revert.
// Fragment layouts (gfx950, verified): A/B: idx=lane&15, k=(lane>>4)*8+j;
// C/D: col=lane&15, row=(lane>>4)*4+reg.

typedef _Float16 half8 __attribute__((ext_vector_type(8)));
typedef float floatx4 __attribute__((ext_vector_type(4)));

#define HSTR 40    // h/pe row stride (f16): 80 B
#define WSTR 104   // wm1t row stride (f16): 208 B
#define GRID_MAIN 1024

__global__ void feat_to_f16(const float* __restrict__ nf,
                            _Float16* __restrict__ o, int n8) {
    int t = blockIdx.x * 256 + threadIdx.x;
    if (t >= n8) return;
    const float4* p = (const float4*)nf + (size_t)t * 2;
    const float4 a = p[0], b = p[1];
    half8 h;
    h[0] = (_Float16)a.x; h[1] = (_Float16)a.y;
    h[2] = (_Float16)a.z; h[3] = (_Float16)a.w;
    h[4] = (_Float16)b.x; h[5] = (_Float16)b.y;
    h[6] = (_Float16)b.z; h[7] = (_Float16)b.w;
    *((half8*)o + t) = h;
}

// load 2 row-tiles (16 regs peak) of node features as MFMA A-fragments
__device__ __forceinline__ void load_feat2(const _Float16* __restrict__ feat16,
                                           const float* __restrict__ node_feat,
                                           int use_f16, int nd0, int nd1, int q,
                                           half8 fA[2][2]) {
    if (use_f16) {
        const _Float16* fb0 = feat16 + (size_t)nd0 * 64 + q * 8;
        const _Float16* fb1 = feat16 + (size_t)nd1 * 64 + q * 8;
        fA[0][0] = *(const half8*)(fb0);
        fA[0][1] = *(const half8*)(fb0 + 32);
        fA[1][0] = *(const half8*)(fb1);
        fA[1][1] = *(const half8*)(fb1 + 32);
    } else {
        #pragma unroll
        for (int rr = 0; rr < 2; ++rr) {
            const float* fb = node_feat + (size_t)(rr ? nd1 : nd0) * 64 + q * 8;
            #pragma unroll
            for (int kt = 0; kt < 2; ++kt) {
                const float4 lo = *(const float4*)(fb + kt * 32);
                const float4 hi = *(const float4*)(fb + kt * 32 + 4);
                half8 h;
                h[0] = (_Float16)lo.x; h[1] = (_Float16)lo.y;
                h[2] = (_Float16)lo.z; h[3] = (_Float16)lo.w;
                h[4] = (_Float16)hi.x; h[5] = (_Float16)hi.y;
                h[6] = (_Float16)hi.z; h[7] = (_Float16)hi.w;
                fA[rr][kt] = h;
            }
        }
    }
}

__global__ __launch_bounds__(256, 4) void neurtw_r15(
    const float* __restrict__ pos_table,   // [NUM_KEYS, 4]
    const float* __restrict__ node_feat,   // [NUM_NODES, 64] fp32 (fallback)
    const float* __restrict__ W1,          // [4, 32]
    const float* __restrict__ b1,          // [32]
    const float* __restrict__ W2,          // [32, 32]
    const float* __restrict__ b2,          // [32]
    const float* __restrict__ Wm1,         // [96, 64]
    const float* __restrict__ bm1,         // [64]
    const float* __restrict__ Wm2,         // [64, 1]
    const float* __restrict__ bm2,         // [1]
    const int*   __restrict__ key_idx,     // [rows]
    const int*   __restrict__ node_idx,    // [rows]
    const _Float16* __restrict__ feat16,   // [NUM_NODES, 64] f16 (ws)
    int use_f16,
    float*       __restrict__ out,         // [rows]
    int rows)
{
    __shared__ _Float16 hpe[256 * HSTR];   // 20 KB (h then pe; wave-private)
    __shared__ _Float16 wm1t[64 * WSTR];   // 13 KB  wm1t[n][k] = Wm1[k][n]

    const int tid  = threadIdx.x;
    const int lane = tid & 63;
    const int r0   = (tid >> 6) * 64;
    const int ln   = lane & 15;
    const int q    = lane >> 4;

    // ---------- once per block: stage Wm1^T into LDS ----------
    #pragma unroll
    for (int i = 0; i < 3; ++i) {
        const int task = i * 256 + tid;
        const int n = task & 63, k8 = task >> 6;
        half8 w;
        #pragma unroll
        for (int kk = 0; kk < 8; ++kk)
            w[kk] = (_Float16)Wm1[(k8 * 8 + kk) * 64 + n];
        *(half8*)(&wm1t[n * WSTR + k8 * 8]) = w;
    }

    // ---------- once per block: per-lane weight/bias fragments ----------
    half8 b_w2[2];
    #pragma unroll
    for (int ct = 0; ct < 2; ++ct)
        #pragma unroll
        for (int j = 0; j < 8; ++j)
            b_w2[ct][j] = (_Float16)W2[(q * 8 + j) * 32 + ct * 16 + ln];
    float b2v[2];
    b2v[0] = b2[ln]; b2v[1] = b2[16 + ln];
    float bm1v[4], wm2v[4];
    #pragma unroll
    for (int ct = 0; ct < 4; ++ct) {
        bm1v[ct] = bm1[ct * 16 + ln];
        wm2v[ct] = Wm2[ct * 16 + ln];
    }
    const float bm2s = bm2[0];

    __syncthreads();   // wm1t staged (the ONLY barrier in the kernel)

    // ---------- pipeline prologue: iter-0 indices + enc ----------
    int base = blockIdx.x * 256;
    int ndr[4];
    #pragma unroll
    for (int rt = 0; rt < 4; ++rt)
        ndr[rt] = node_idx[base + r0 + rt * 16 + ln];
    int kkc = key_idx[base + tid];
    float4 enc = *(const float4*)(pos_table + (size_t)kkc * 4);

    while (base < rows) {
        const int nbase = base + GRID_MAIN * 256;
        const bool more = nbase < rows;

        // ---- half-A feat gathers: issue at cycle 0 (ndr resident) ----
        half8 fA[2][2];
        load_feat2(feat16, node_feat, use_f16, ndr[0], ndr[1], q, fA);

        // ---- next-iter independent index loads ----
        int ndr_n[4];
        int kk_n;
        if (more) {
            #pragma unroll
            for (int rt = 0; rt < 4; ++rt)
                ndr_n[rt] = node_idx[nbase + r0 + rt * 16 + ln];
            kk_n = key_idx[nbase + tid];
        } else {
            #pragma unroll
            for (int rt = 0; rt < 4; ++rt)
                ndr_n[rt] = 0;
            kk_n = 0;
        }

        // ---- GEMM1 (VALU fp32, enc resident) -> h, all 64 wave rows ----
        #pragma unroll
        for (int g = 0; g < 4; ++g) {
            half8 hv;
            #pragma unroll
            for (int j8 = 0; j8 < 8; ++j8) {
                const int j = g * 8 + j8;
                float a = fmaf(enc.w, W1[96 + j],
                          fmaf(enc.z, W1[64 + j],
                          fmaf(enc.y, W1[32 + j],
                          fmaf(enc.x, W1[j], b1[j]))));
                hv[j8] = (_Float16)fmaxf(a, 0.0f);
            }
            *(half8*)(&hpe[tid * HSTR + g * 8]) = hv;
        }

        // ---- GEMM2 streamed per-rt: read a_h, 2 MFMA, write pe ----
        // (rt's h-tile rows [r0+rt*16, +16) fully consumed by its own
        //  A-fragment read before pe overwrites the same rows)
        #pragma unroll
        for (int rt = 0; rt < 4; ++rt) {
            const half8 ah = *(const half8*)(&hpe[(r0 + rt * 16 + ln) * HSTR + q * 8]);
            floatx4 z0 = {0.f, 0.f, 0.f, 0.f};
            floatx4 z1 = {0.f, 0.f, 0.f, 0.f};
            const floatx4 p0 = __builtin_amdgcn_mfma_f32_16x16x32_f16(ah, b_w2[0], z0, 0, 0, 0);
            const floatx4 p1 = __builtin_amdgcn_mfma_f32_16x16x32_f16(ah, b_w2[1], z1, 0, 0, 0);
            #pragma unroll
            for (int r = 0; r < 4; ++r) {
                hpe[(r0 + rt * 16 + q * 4 + r) * HSTR + ln]      = (_Float16)(p0[r] + b2v[0]);
                hpe[(r0 + rt * 16 + q * 4 + r) * HSTR + 16 + ln] = (_Float16)(p1[r] + b2v[1]);
            }
        }

        // ---- next-iter enc gather (kk_n has had GEMM1+GEMM2 to land) ----
        float4 enc_n = enc;
        if (more)
            enc_n = *(const float4*)(pos_table + (size_t)kk_n * 4);

        floatx4 acc[2][4];

        // ================= HALF A: row-tiles 0,1 =================
        #pragma unroll
        for (int ct = 0; ct < 4; ++ct) {
            const float bb = bm1v[ct];
            acc[0][ct] = (floatx4){bb, bb, bb, bb};
            acc[1][ct] = (floatx4){bb, bb, bb, bb};
        }

        // feat ktiles (consume fA = half-A fragments)
        #pragma unroll
        for (int kt = 0; kt < 2; ++kt) {
            half8 bk[4];
            #pragma unroll
            for (int ct = 0; ct < 4; ++ct)
                bk[ct] = *(const half8*)(&wm1t[(ct * 16 + ln) * WSTR + 32 + kt * 32 + q * 8]);
            #pragma unroll
            for (int rr = 0; rr < 2; ++rr)
                #pragma unroll
                for (int ct = 0; ct < 4; ++ct)
                    acc[rr][ct] = __builtin_amdgcn_mfma_f32_16x16x32_f16(
                        fA[rr][kt], bk[ct], acc[rr][ct], 0, 0, 0);
        }

        // half-A fA consumed -> issue half-B feat gathers into fA now;
        // latency covered by pe-ktile-A + GEMM4-A + pe-ktile-B ds/MFMA work
        load_feat2(feat16, node_feat, use_f16, ndr[2], ndr[3], q, fA);

        // pe ktile A
        {
            half8 b0[4];
            #pragma unroll
            for (int ct = 0; ct < 4; ++ct)
                b0[ct] = *(const half8*)(&wm1t[(ct * 16 + ln) * WSTR + q * 8]);
            #pragma unroll
            for (int rr = 0; rr < 2; ++rr) {
                const half8 ap = *(const half8*)(&hpe[(r0 + rr * 16 + ln) * HSTR + q * 8]);
                #pragma unroll
                for (int ct = 0; ct < 4; ++ct)
                    acc[rr][ct] = __builtin_amdgcn_mfma_f32_16x16x32_f16(
                        ap, b0[ct], acc[rr][ct], 0, 0, 0);
            }
        }

        // GEMM4 A
        #pragma unroll
        for (int rr = 0; rr < 2; ++rr) {
            #pragma unroll
            for (int r = 0; r < 4; ++r) {
                float p = 0.0f;
                #pragma unroll
                for (int ct = 0; ct < 4; ++ct)
                    p = fmaf(fmaxf(acc[rr][ct][r], 0.0f), wm2v[ct], p);
                p += __shfl_xor(p, 1);
                p += __shfl_xor(p, 2);
                p += __shfl_xor(p, 4);
                p += __shfl_xor(p, 8);
                if (ln == 0)
                    out[base + r0 + rr * 16 + q * 4 + r] = p + bm2s;
            }
        }

        // ================= HALF B: row-tiles 2,3 =================
        #pragma unroll
        for (int ct = 0; ct < 4; ++ct) {
            const float bb = bm1v[ct];
            acc[0][ct] = (floatx4){bb, bb, bb, bb};
            acc[1][ct] = (floatx4){bb, bb, bb, bb};
        }

        // pe ktile B first (gives the just-issued fA gathers more slack)
        {
            half8 b0[4];
            #pragma unroll
            for (int ct = 0; ct < 4; ++ct)
                b0[ct] = *(const half8*)(&wm1t[(ct * 16 + ln) * WSTR + q * 8]);
            #pragma unroll
            for (int rr = 0; rr < 2; ++rr) {
                const half8 ap = *(const half8*)(&hpe[(r0 + (2 + rr) * 16 + ln) * HSTR + q * 8]);
                #pragma unroll
                for (int ct = 0; ct < 4; ++ct)
                    acc[rr][ct] = __builtin_amdgcn_mfma_f32_16x16x32_f16(
                        ap, b0[ct], acc[rr][ct], 0, 0, 0);
            }
        }

        // feat ktiles B (consume fA = half-B fragments)
        #pragma unroll
        for (int kt = 0; kt < 2; ++kt) {
            half8 bk[4];
            #pragma unroll
            for (int ct = 0; ct < 4; ++ct)
                bk[ct] = *(const half8*)(&wm1t[(ct * 16 + ln) * WSTR + 32 + kt * 32 + q * 8]);
            #pragma unroll
            for (int rr = 0; rr < 2; ++rr)
                #pragma unroll
                for (int ct = 0; ct < 4; ++ct)
                    acc[rr][ct] = __builtin_amdgcn_mfma_f32_16x16x32_f16(
                        fA[rr][kt], bk[ct], acc[rr][ct], 0, 0, 0);
        }

        // GEMM4 B
        #pragma unroll
        for (int rr = 0; rr < 2; ++rr) {
            #pragma unroll
            for (int r = 0; r < 4; ++r) {
                float p = 0.0f;
                #pragma unroll
                for (int ct = 0; ct < 4; ++ct)
                    p = fmaf(fmaxf(acc[rr][ct][r], 0.0f), wm2v[ct], p);
                p += __shfl_xor(p, 1);
                p += __shfl_xor(p, 2);
                p += __shfl_xor(p, 4);
                p += __shfl_xor(p, 8);
                if (ln == 0)
                    out[base + r0 + (2 + rr) * 16 + q * 4 + r] = p + bm2s;
            }
        }

        // ---- rotate pipeline state ----
        base = nbase;
        #pragma unroll
        for (int rt = 0; rt < 4; ++rt)
            ndr[rt] = ndr_n[rt];
        kkc = kk_n;
        enc = enc_n;
    }
}

extern "C" void kernel_launch(void* const* d_in, const int* in_sizes, int n_in,
                              void* d_out, int out_size, void* d_ws, size_t ws_size,
                              hipStream_t stream) {
    const float* pos_table = (const float*)d_in[0];
    const float* node_feat = (const float*)d_in[1];
    const float* W1        = (const float*)d_in[2];
    const float* b1        = (const float*)d_in[3];
    const float* W2        = (const float*)d_in[4];
    const float* b2        = (const float*)d_in[5];
    const float* Wm1       = (const float*)d_in[6];
    const float* bm1       = (const float*)d_in[7];
    const float* Wm2       = (const float*)d_in[8];
    const float* bm2       = (const float*)d_in[9];
    const int*   key_idx   = (const int*)d_in[10];
    const int*   node_idx  = (const int*)d_in[11];
    float* out = (float*)d_out;

    const int rows  = in_sizes[10];                // 1,048,576
    const int nfeat = in_sizes[1];                 // NUM_NODES*64

    _Float16* feat16 = (_Float16*)d_ws;
    const size_t need = (size_t)nfeat * sizeof(_Float16);
    const int use_f16 = (ws_size >= need) ? 1 : 0;

    if (use_f16) {
        const int n8 = nfeat / 8;
        feat_to_f16<<<(n8 + 255) / 256, 256, 0, stream>>>(node_feat, feat16, n8);
    }

    neurtw_r15<<<GRID_MAIN, 256, 0, stream>>>(
        pos_table, node_feat, W1, b1, W2, b2, Wm1, bm1, Wm2, bm2,
        key_idx, node_idx, feat16, use_f16, out, rows);
}

// Round 6
// 167.153 us; speedup vs baseline: 1.0630x; 1.0630x over previous
//
#include <hip/hip_runtime.h>

// NeurTWs R16 = R14 body (59us steady, 84 VGPR, no spill, 3 blocks/CU,
// cross-iter ndr/kk/enc prefetch) + pos_table f32->f16 compaction.
// R15 post-mortem closed the 4-wave path: THREE launch_bounds(256,4)
// attempts (R11 cosmetic, R13 LDS-tables, R15 structural acc/fA halving)
// all spilled (WRITE 56-81MB) -- the scheduler's live-range extension for
// latency hiding pushes every variant past 128 regs. Locked model from
// R10-R15: T = traffic / BW(waves); 3 waves sustain 2.4-3.0 TB/s. At
// fixed waves the lever is TRAFFIC. Decomposition of R14's 156MB FETCH:
// pos gathers ~50-60MB (1M random 16B reads over 16MB = 262K 64B lines,
// ~3x thrash re-fetch), feat ~70-90MB, idx 8MB. pos f32->f16: table
// 16->8MB = half the lines, 8 keys/line, combined gather footprint
// 28.8->20.8MB -> better L2 retention for both tables. Accuracy: enc
// f16 err <= 2^-12, through three ~0.05-scale layers -> ~1e-4 at out,
// well under the 0.0039 baseline absmax. ws = feat16 12.8MB + pos16 8MB
// (guarded, falls back to f32). Everything else byte-for-byte R14.
// Fragment layouts (gfx950, verified): A/B: idx=lane&15, k=(lane>>4)*8+j;
// C/D: col=lane&15, row=(lane>>4)*4+reg.

typedef _Float16 half8 __attribute__((ext_vector_type(8)));
typedef _Float16 half4 __attribute__((ext_vector_type(4)));
typedef float floatx4 __attribute__((ext_vector_type(4)));

#define HSTR 40    // h/pe row stride (f16): 80 B
#define WSTR 104   // wm1t row stride (f16): 208 B
#define GRID_MAIN 768

__global__ void feat_to_f16(const float* __restrict__ nf,
                            _Float16* __restrict__ o, int n8) {
    int t = blockIdx.x * 256 + threadIdx.x;
    if (t >= n8) return;
    const float4* p = (const float4*)nf + (size_t)t * 2;
    const float4 a = p[0], b = p[1];
    half8 h;
    h[0] = (_Float16)a.x; h[1] = (_Float16)a.y;
    h[2] = (_Float16)a.z; h[3] = (_Float16)a.w;
    h[4] = (_Float16)b.x; h[5] = (_Float16)b.y;
    h[6] = (_Float16)b.z; h[7] = (_Float16)b.w;
    *((half8*)o + t) = h;
}

__device__ __forceinline__ void load_feat(const _Float16* __restrict__ feat16,
                                          const float* __restrict__ node_feat,
                                          int use_f16, const int* ndr, int q,
                                          half8 fA[4][2]) {
    if (use_f16) {
        #pragma unroll
        for (int rt = 0; rt < 4; ++rt) {
            const _Float16* fb = feat16 + (size_t)ndr[rt] * 64 + q * 8;
            fA[rt][0] = *(const half8*)(fb);
            fA[rt][1] = *(const half8*)(fb + 32);
        }
    } else {
        #pragma unroll
        for (int rt = 0; rt < 4; ++rt) {
            const float* fb = node_feat + (size_t)ndr[rt] * 64 + q * 8;
            #pragma unroll
            for (int kt = 0; kt < 2; ++kt) {
                const float4 lo = *(const float4*)(fb + kt * 32);
                const float4 hi = *(const float4*)(fb + kt * 32 + 4);
                half8 h;
                h[0] = (_Float16)lo.x; h[1] = (_Float16)lo.y;
                h[2] = (_Float16)lo.z; h[3] = (_Float16)lo.w;
                h[4] = (_Float16)hi.x; h[5] = (_Float16)hi.y;
                h[6] = (_Float16)hi.z; h[7] = (_Float16)hi.w;
                fA[rt][kt] = h;
            }
        }
    }
}

__global__ __launch_bounds__(256, 3) void neurtw_r16(
    const float* __restrict__ pos_table,   // [NUM_KEYS, 4]
    const float* __restrict__ node_feat,   // [NUM_NODES, 64] fp32 (fallback)
    const float* __restrict__ W1,          // [4, 32]
    const float* __restrict__ b1,          // [32]
    const float* __restrict__ W2,          // [32, 32]
    const float* __restrict__ b2,          // [32]
    const float* __restrict__ Wm1,         // [96, 64]
    const float* __restrict__ bm1,         // [64]
    const float* __restrict__ Wm2,         // [64, 1]
    const float* __restrict__ bm2,         // [1]
    const int*   __restrict__ key_idx,     // [rows]
    const int*   __restrict__ node_idx,    // [rows]
    const _Float16* __restrict__ feat16,   // [NUM_NODES, 64] f16 (ws)
    const _Float16* __restrict__ pos16,    // [NUM_KEYS, 4] f16 (ws)
    int use_f16, int use_pos16,
    float*       __restrict__ out,         // [rows]
    int rows)
{
    __shared__ _Float16 hpe[256 * HSTR];   // 20 KB (h then pe; wave-private)
    __shared__ _Float16 wm1t[64 * WSTR];   // 13 KB  wm1t[n][k] = Wm1[k][n]

    const int tid  = threadIdx.x;
    const int lane = tid & 63;
    const int r0   = (tid >> 6) * 64;
    const int ln   = lane & 15;
    const int q    = lane >> 4;

    // ---------- once per block: stage Wm1^T into LDS ----------
    #pragma unroll
    for (int i = 0; i < 3; ++i) {
        const int task = i * 256 + tid;
        const int n = task & 63, k8 = task >> 6;
        half8 w;
        #pragma unroll
        for (int kk = 0; kk < 8; ++kk)
            w[kk] = (_Float16)Wm1[(k8 * 8 + kk) * 64 + n];
        *(half8*)(&wm1t[n * WSTR + k8 * 8]) = w;
    }

    // ---------- once per block: per-lane weight/bias fragments ----------
    half8 b_w2[2];
    #pragma unroll
    for (int ct = 0; ct < 2; ++ct)
        #pragma unroll
        for (int j = 0; j < 8; ++j)
            b_w2[ct][j] = (_Float16)W2[(q * 8 + j) * 32 + ct * 16 + ln];
    float b2v[2];
    b2v[0] = b2[ln]; b2v[1] = b2[16 + ln];
    float bm1v[4], wm2v[4];
    #pragma unroll
    for (int ct = 0; ct < 4; ++ct) {
        bm1v[ct] = bm1[ct * 16 + ln];
        wm2v[ct] = Wm2[ct * 16 + ln];
    }
    const float bm2s = bm2[0];

    __syncthreads();   // wm1t staged (the ONLY barrier in the kernel)

    // ---------- pipeline prologue: iter-0 indices + enc ----------
    int base = blockIdx.x * 256;
    int ndr[4];
    #pragma unroll
    for (int rt = 0; rt < 4; ++rt)
        ndr[rt] = node_idx[base + r0 + rt * 16 + ln];
    int kkc = key_idx[base + tid];
    float4 enc;
    if (use_pos16) {
        const half4 e = *(const half4*)(pos16 + (size_t)kkc * 4);
        enc.x = (float)e[0]; enc.y = (float)e[1];
        enc.z = (float)e[2]; enc.w = (float)e[3];
    } else {
        enc = *(const float4*)(pos_table + (size_t)kkc * 4);
    }

    while (base < rows) {
        const int nbase = base + GRID_MAIN * 256;
        const bool more = nbase < rows;

        // ---- 1) current feat gathers: issue at cycle 0 (ndr resident) ----
        half8 fA[4][2];
        load_feat(feat16, node_feat, use_f16, ndr, q, fA);

        // ---- 2) next-iter independent index loads ----
        int ndr_n[4];
        int kk_n;
        if (more) {
            #pragma unroll
            for (int rt = 0; rt < 4; ++rt)
                ndr_n[rt] = node_idx[nbase + r0 + rt * 16 + ln];
            kk_n = key_idx[nbase + tid];
        } else {
            #pragma unroll
            for (int rt = 0; rt < 4; ++rt)
                ndr_n[rt] = 0;
            kk_n = 0;
        }

        // ---- GEMM1 (VALU fp32, enc already resident) -> h ----
        #pragma unroll
        for (int g = 0; g < 4; ++g) {
            half8 hv;
            #pragma unroll
            for (int j8 = 0; j8 < 8; ++j8) {
                const int j = g * 8 + j8;
                float a = fmaf(enc.w, W1[96 + j],
                          fmaf(enc.z, W1[64 + j],
                          fmaf(enc.y, W1[32 + j],
                          fmaf(enc.x, W1[j], b1[j]))));
                hv[j8] = (_Float16)fmaxf(a, 0.0f);
            }
            *(half8*)(&hpe[tid * HSTR + g * 8]) = hv;
        }
        // wave-private transpose read — no barrier (same wave wrote it)
        half8 a_h[4];
        #pragma unroll
        for (int rt = 0; rt < 4; ++rt)
            a_h[rt] = *(const half8*)(&hpe[(r0 + rt * 16 + ln) * HSTR + q * 8]);

        // ---- GEMM2: 8 MFMA -> pe (C-layout regs) ----
        floatx4 pc[4][2];
        #pragma unroll
        for (int rt = 0; rt < 4; ++rt)
            #pragma unroll
            for (int ct = 0; ct < 2; ++ct) {
                floatx4 c = {0.f, 0.f, 0.f, 0.f};
                pc[rt][ct] = __builtin_amdgcn_mfma_f32_16x16x32_f16(
                    a_h[rt], b_w2[ct], c, 0, 0, 0);
            }

        // write pe into the SAME buffer (h consumed; own wave's slice only)
        #pragma unroll
        for (int rt = 0; rt < 4; ++rt)
            #pragma unroll
            for (int ct = 0; ct < 2; ++ct)
                #pragma unroll
                for (int r = 0; r < 4; ++r)
                    hpe[(r0 + rt * 16 + q * 4 + r) * HSTR + ct * 16 + ln] =
                        (_Float16)(pc[rt][ct][r] + b2v[ct]);
        // no barrier: reader below is the same wave

        // ---- next-iter enc gather (kk_n has had GEMM1+GEMM2 to land) ----
        float4 enc_n = enc;
        if (more) {
            if (use_pos16) {
                const half4 e = *(const half4*)(pos16 + (size_t)kk_n * 4);
                enc_n.x = (float)e[0]; enc_n.y = (float)e[1];
                enc_n.z = (float)e[2]; enc_n.w = (float)e[3];
            } else {
                enc_n = *(const float4*)(pos_table + (size_t)kk_n * 4);
            }
        }

        // ---- GEMM3: 48 MFMA ----
        floatx4 acc[4][4];
        #pragma unroll
        for (int ct = 0; ct < 4; ++ct) {
            const float bb = bm1v[ct];
            #pragma unroll
            for (int rt = 0; rt < 4; ++rt)
                acc[rt][ct] = (floatx4){bb, bb, bb, bb};
        }

        {   // ktile 0: A = pe from LDS
            half8 a_pe[4];
            #pragma unroll
            for (int rt = 0; rt < 4; ++rt)
                a_pe[rt] = *(const half8*)(&hpe[(r0 + rt * 16 + ln) * HSTR + q * 8]);
            half8 b0[4];
            #pragma unroll
            for (int ct = 0; ct < 4; ++ct)
                b0[ct] = *(const half8*)(&wm1t[(ct * 16 + ln) * WSTR + q * 8]);
            #pragma unroll
            for (int rt = 0; rt < 4; ++rt)
                #pragma unroll
                for (int ct = 0; ct < 4; ++ct)
                    acc[rt][ct] = __builtin_amdgcn_mfma_f32_16x16x32_f16(
                        a_pe[rt], b0[ct], acc[rt][ct], 0, 0, 0);
        }

        #pragma unroll
        for (int kt = 0; kt < 2; ++kt) {   // ktiles 1,2: A = feat (prefetched)
            half8 bk[4];
            #pragma unroll
            for (int ct = 0; ct < 4; ++ct)
                bk[ct] = *(const half8*)(&wm1t[(ct * 16 + ln) * WSTR + 32 + kt * 32 + q * 8]);
            #pragma unroll
            for (int rt = 0; rt < 4; ++rt)
                #pragma unroll
                for (int ct = 0; ct < 4; ++ct)
                    acc[rt][ct] = __builtin_amdgcn_mfma_f32_16x16x32_f16(
                        fA[rt][kt], bk[ct], acc[rt][ct], 0, 0, 0);
        }

        // ---- GEMM4: relu + Wm2 dot + 4-step butterfly + store ----
        #pragma unroll
        for (int rt = 0; rt < 4; ++rt) {
            #pragma unroll
            for (int r = 0; r < 4; ++r) {
                float p = 0.0f;
                #pragma unroll
                for (int ct = 0; ct < 4; ++ct)
                    p = fmaf(fmaxf(acc[rt][ct][r], 0.0f), wm2v[ct], p);
                p += __shfl_xor(p, 1);
                p += __shfl_xor(p, 2);
                p += __shfl_xor(p, 4);
                p += __shfl_xor(p, 8);
                if (ln == 0)
                    out[base + r0 + rt * 16 + q * 4 + r] = p + bm2s;
            }
        }

        // ---- rotate pipeline state ----
        base = nbase;
        #pragma unroll
        for (int rt = 0; rt < 4; ++rt)
            ndr[rt] = ndr_n[rt];
        kkc = kk_n;
        enc = enc_n;
    }
}

extern "C" void kernel_launch(void* const* d_in, const int* in_sizes, int n_in,
                              void* d_out, int out_size, void* d_ws, size_t ws_size,
                              hipStream_t stream) {
    const float* pos_table = (const float*)d_in[0];
    const float* node_feat = (const float*)d_in[1];
    const float* W1        = (const float*)d_in[2];
    const float* b1        = (const float*)d_in[3];
    const float* W2        = (const float*)d_in[4];
    const float* b2        = (const float*)d_in[5];
    const float* Wm1       = (const float*)d_in[6];
    const float* bm1       = (const float*)d_in[7];
    const float* Wm2       = (const float*)d_in[8];
    const float* bm2       = (const float*)d_in[9];
    const int*   key_idx   = (const int*)d_in[10];
    const int*   node_idx  = (const int*)d_in[11];
    float* out = (float*)d_out;

    const int rows  = in_sizes[10];                // 1,048,576
    const int nfeat = in_sizes[1];                 // NUM_NODES*64
    const int npos  = in_sizes[0];                 // NUM_KEYS*4

    _Float16* feat16 = (_Float16*)d_ws;
    const size_t need_feat = (size_t)nfeat * sizeof(_Float16);
    const int use_f16 = (ws_size >= need_feat) ? 1 : 0;

    _Float16* pos16 = (_Float16*)((char*)d_ws + need_feat);
    const size_t need_pos = (size_t)npos * sizeof(_Float16);
    const int use_pos16 = (ws_size >= need_feat + need_pos) ? 1 : 0;

    if (use_f16) {
        const int n8 = nfeat / 8;
        feat_to_f16<<<(n8 + 255) / 256, 256, 0, stream>>>(node_feat, feat16, n8);
    }
    if (use_pos16) {
        const int n8p = npos / 8;
        feat_to_f16<<<(n8p + 255) / 256, 256, 0, stream>>>(pos_table, pos16, n8p);
    }

    neurtw_r16<<<GRID_MAIN, 256, 0, stream>>>(
        pos_table, node_feat, W1, b1, W2, b2, Wm1, bm1, Wm2, bm2,
        key_idx, node_idx, feat16, pos16, use_f16, use_pos16, out, rows);
}

// Round 7
// 154.239 us; speedup vs baseline: 1.1520x; 1.0837x over previous
//
#include <hip/hip_runtime.h>

// NeurTWs R17 = R14 body (best steady 59us, 84 VGPR, no spill, 3 blocks/
// CU, cross-iter ndr/kk/enc prefetch) + half-deep cross-iter FEAT
// prefetch. R16 post-mortem: pos16 regressed (66us, FETCH -4MB only, BW
// 3.0->2.66) -- pos gathers are not the thrash term; reverted.
// Issue-budget model (R14 counters): per wave/iter ~1200cy VALU + 360
// MFMA + 600 DS = 2200cy issue; x3 waves/SIMD = 6600 vs 9150 wall ->
// ~72% issue-occupied, ~2500cy residual stall = feat-gather latency
// (only loads with <1-iter cover: issued at top, consumed in ktiles 1,2
// ~1000cy later vs up to ~900cy HBM-miss latency, jitter-exposed at 3
// waves). Fix within the 3-wave budget: VGPR cap for 3 waves is
// floor(512/3)-64 = ~106 arch; R14 uses 84 -> 22 free. Spend 16:
//   - fA01 (rt 0,1) for iter i+1 issued right after iter i's ktile-2
//     consumes fA (ndr_n arrived ~1500cy earlier; cover = GEMM4 + next
//     GEMM1/2 ~1800cy >> 900).
//   - iter top loads only fA23 (keeps its ~1000cy GEMM1/2+ktile0 cover).
// Decisive counters: VGPR_Count <= 106 and WRITE_SIZE ~19MB = no spill.
// Pre-commit: >=58us => residual stall is NOT feat latency => pivot to
// issue-work reduction (GEMM1 via MFMA, GEMM4 shfl cuts).
// Fragment layouts (gfx950, verified): A/B: idx=lane&15, k=(lane>>4)*8+j;
// C/D: col=lane&15, row=(lane>>4)*4+reg.

typedef _Float16 half8 __attribute__((ext_vector_type(8)));
typedef float floatx4 __attribute__((ext_vector_type(4)));

#define HSTR 40    // h/pe row stride (f16): 80 B
#define WSTR 104   // wm1t row stride (f16): 208 B
#define GRID_MAIN 768

__global__ void feat_to_f16(const float* __restrict__ nf,
                            _Float16* __restrict__ o, int n8) {
    int t = blockIdx.x * 256 + threadIdx.x;
    if (t >= n8) return;
    const float4* p = (const float4*)nf + (size_t)t * 2;
    const float4 a = p[0], b = p[1];
    half8 h;
    h[0] = (_Float16)a.x; h[1] = (_Float16)a.y;
    h[2] = (_Float16)a.z; h[3] = (_Float16)a.w;
    h[4] = (_Float16)b.x; h[5] = (_Float16)b.y;
    h[6] = (_Float16)b.z; h[7] = (_Float16)b.w;
    *((half8*)o + t) = h;
}

// load feat A-fragments for 2 row-tiles (nd0 -> fA[0], nd1 -> fA[1])
__device__ __forceinline__ void load_feat2(const _Float16* __restrict__ feat16,
                                           const float* __restrict__ node_feat,
                                           int use_f16, int nd0, int nd1, int q,
                                           half8 fA[2][2]) {
    if (use_f16) {
        const _Float16* fb0 = feat16 + (size_t)nd0 * 64 + q * 8;
        const _Float16* fb1 = feat16 + (size_t)nd1 * 64 + q * 8;
        fA[0][0] = *(const half8*)(fb0);
        fA[0][1] = *(const half8*)(fb0 + 32);
        fA[1][0] = *(const half8*)(fb1);
        fA[1][1] = *(const half8*)(fb1 + 32);
    } else {
        #pragma unroll
        for (int rr = 0; rr < 2; ++rr) {
            const float* fb = node_feat + (size_t)(rr ? nd1 : nd0) * 64 + q * 8;
            #pragma unroll
            for (int kt = 0; kt < 2; ++kt) {
                const float4 lo = *(const float4*)(fb + kt * 32);
                const float4 hi = *(const float4*)(fb + kt * 32 + 4);
                half8 h;
                h[0] = (_Float16)lo.x; h[1] = (_Float16)lo.y;
                h[2] = (_Float16)lo.z; h[3] = (_Float16)lo.w;
                h[4] = (_Float16)hi.x; h[5] = (_Float16)hi.y;
                h[6] = (_Float16)hi.z; h[7] = (_Float16)hi.w;
                fA[rr][kt] = h;
            }
        }
    }
}

__global__ __launch_bounds__(256, 3) void neurtw_r17(
    const float* __restrict__ pos_table,   // [NUM_KEYS, 4]
    const float* __restrict__ node_feat,   // [NUM_NODES, 64] fp32 (fallback)
    const float* __restrict__ W1,          // [4, 32]
    const float* __restrict__ b1,          // [32]
    const float* __restrict__ W2,          // [32, 32]
    const float* __restrict__ b2,          // [32]
    const float* __restrict__ Wm1,         // [96, 64]
    const float* __restrict__ bm1,         // [64]
    const float* __restrict__ Wm2,         // [64, 1]
    const float* __restrict__ bm2,         // [1]
    const int*   __restrict__ key_idx,     // [rows]
    const int*   __restrict__ node_idx,    // [rows]
    const _Float16* __restrict__ feat16,   // [NUM_NODES, 64] f16 (ws)
    int use_f16,
    float*       __restrict__ out,         // [rows]
    int rows)
{
    __shared__ _Float16 hpe[256 * HSTR];   // 20 KB (h then pe; wave-private)
    __shared__ _Float16 wm1t[64 * WSTR];   // 13 KB  wm1t[n][k] = Wm1[k][n]

    const int tid  = threadIdx.x;
    const int lane = tid & 63;
    const int r0   = (tid >> 6) * 64;
    const int ln   = lane & 15;
    const int q    = lane >> 4;

    // ---------- once per block: stage Wm1^T into LDS ----------
    #pragma unroll
    for (int i = 0; i < 3; ++i) {
        const int task = i * 256 + tid;
        const int n = task & 63, k8 = task >> 6;
        half8 w;
        #pragma unroll
        for (int kk = 0; kk < 8; ++kk)
            w[kk] = (_Float16)Wm1[(k8 * 8 + kk) * 64 + n];
        *(half8*)(&wm1t[n * WSTR + k8 * 8]) = w;
    }

    // ---------- once per block: per-lane weight/bias fragments ----------
    half8 b_w2[2];
    #pragma unroll
    for (int ct = 0; ct < 2; ++ct)
        #pragma unroll
        for (int j = 0; j < 8; ++j)
            b_w2[ct][j] = (_Float16)W2[(q * 8 + j) * 32 + ct * 16 + ln];
    float b2v[2];
    b2v[0] = b2[ln]; b2v[1] = b2[16 + ln];
    float bm1v[4], wm2v[4];
    #pragma unroll
    for (int ct = 0; ct < 4; ++ct) {
        bm1v[ct] = bm1[ct * 16 + ln];
        wm2v[ct] = Wm2[ct * 16 + ln];
    }
    const float bm2s = bm2[0];

    __syncthreads();   // wm1t staged (the ONLY barrier in the kernel)

    // ---------- pipeline prologue: iter-0 indices + enc + fA01 ----------
    int base = blockIdx.x * 256;
    int ndr[4];
    #pragma unroll
    for (int rt = 0; rt < 4; ++rt)
        ndr[rt] = node_idx[base + r0 + rt * 16 + ln];
    int kkc = key_idx[base + tid];
    float4 enc = *(const float4*)(pos_table + (size_t)kkc * 4);
    half8 fA01[2][2];
    load_feat2(feat16, node_feat, use_f16, ndr[0], ndr[1], q, fA01);

    while (base < rows) {
        const int nbase = base + GRID_MAIN * 256;
        const bool more = nbase < rows;

        // ---- iter top: only the rt{2,3} feat gathers (ndr resident) ----
        half8 fA23[2][2];
        load_feat2(feat16, node_feat, use_f16, ndr[2], ndr[3], q, fA23);

        // ---- next-iter independent index loads ----
        int ndr_n[4];
        int kk_n;
        if (more) {
            #pragma unroll
            for (int rt = 0; rt < 4; ++rt)
                ndr_n[rt] = node_idx[nbase + r0 + rt * 16 + ln];
            kk_n = key_idx[nbase + tid];
        } else {
            #pragma unroll
            for (int rt = 0; rt < 4; ++rt)
                ndr_n[rt] = 0;
            kk_n = 0;
        }

        // ---- GEMM1 (VALU fp32, enc already resident) -> h ----
        #pragma unroll
        for (int g = 0; g < 4; ++g) {
            half8 hv;
            #pragma unroll
            for (int j8 = 0; j8 < 8; ++j8) {
                const int j = g * 8 + j8;
                float a = fmaf(enc.w, W1[96 + j],
                          fmaf(enc.z, W1[64 + j],
                          fmaf(enc.y, W1[32 + j],
                          fmaf(enc.x, W1[j], b1[j]))));
                hv[j8] = (_Float16)fmaxf(a, 0.0f);
            }
            *(half8*)(&hpe[tid * HSTR + g * 8]) = hv;
        }
        // wave-private transpose read — no barrier (same wave wrote it)
        half8 a_h[4];
        #pragma unroll
        for (int rt = 0; rt < 4; ++rt)
            a_h[rt] = *(const half8*)(&hpe[(r0 + rt * 16 + ln) * HSTR + q * 8]);

        // ---- GEMM2: 8 MFMA -> pe (C-layout regs) ----
        floatx4 pc[4][2];
        #pragma unroll
        for (int rt = 0; rt < 4; ++rt)
            #pragma unroll
            for (int ct = 0; ct < 2; ++ct) {
                floatx4 c = {0.f, 0.f, 0.f, 0.f};
                pc[rt][ct] = __builtin_amdgcn_mfma_f32_16x16x32_f16(
                    a_h[rt], b_w2[ct], c, 0, 0, 0);
            }

        // write pe into the SAME buffer (h consumed; own wave's slice only)
        #pragma unroll
        for (int rt = 0; rt < 4; ++rt)
            #pragma unroll
            for (int ct = 0; ct < 2; ++ct)
                #pragma unroll
                for (int r = 0; r < 4; ++r)
                    hpe[(r0 + rt * 16 + q * 4 + r) * HSTR + ct * 16 + ln] =
                        (_Float16)(pc[rt][ct][r] + b2v[ct]);
        // no barrier: reader below is the same wave

        // ---- next-iter enc gather (kk_n has had GEMM1+GEMM2 to land) ----
        float4 enc_n = enc;
        if (more)
            enc_n = *(const float4*)(pos_table + (size_t)kk_n * 4);

        // ---- GEMM3: 48 MFMA ----
        floatx4 acc[4][4];
        #pragma unroll
        for (int ct = 0; ct < 4; ++ct) {
            const float bb = bm1v[ct];
            #pragma unroll
            for (int rt = 0; rt < 4; ++rt)
                acc[rt][ct] = (floatx4){bb, bb, bb, bb};
        }

        {   // ktile 0: A = pe from LDS
            half8 a_pe[4];
            #pragma unroll
            for (int rt = 0; rt < 4; ++rt)
                a_pe[rt] = *(const half8*)(&hpe[(r0 + rt * 16 + ln) * HSTR + q * 8]);
            half8 b0[4];
            #pragma unroll
            for (int ct = 0; ct < 4; ++ct)
                b0[ct] = *(const half8*)(&wm1t[(ct * 16 + ln) * WSTR + q * 8]);
            #pragma unroll
            for (int rt = 0; rt < 4; ++rt)
                #pragma unroll
                for (int ct = 0; ct < 4; ++ct)
                    acc[rt][ct] = __builtin_amdgcn_mfma_f32_16x16x32_f16(
                        a_pe[rt], b0[ct], acc[rt][ct], 0, 0, 0);
        }

        #pragma unroll
        for (int kt = 0; kt < 2; ++kt) {   // ktiles 1,2: A = feat
            half8 bk[4];
            #pragma unroll
            for (int ct = 0; ct < 4; ++ct)
                bk[ct] = *(const half8*)(&wm1t[(ct * 16 + ln) * WSTR + 32 + kt * 32 + q * 8]);
            #pragma unroll
            for (int ct = 0; ct < 4; ++ct) {
                acc[0][ct] = __builtin_amdgcn_mfma_f32_16x16x32_f16(
                    fA01[0][kt], bk[ct], acc[0][ct], 0, 0, 0);
                acc[1][ct] = __builtin_amdgcn_mfma_f32_16x16x32_f16(
                    fA01[1][kt], bk[ct], acc[1][ct], 0, 0, 0);
                acc[2][ct] = __builtin_amdgcn_mfma_f32_16x16x32_f16(
                    fA23[0][kt], bk[ct], acc[2][ct], 0, 0, 0);
                acc[3][ct] = __builtin_amdgcn_mfma_f32_16x16x32_f16(
                    fA23[1][kt], bk[ct], acc[3][ct], 0, 0, 0);
            }
        }

        // ---- fA consumed: prefetch NEXT-iter fA01 (rt 0,1) now ----
        // ndr_n arrived ~1500cy ago; cover = GEMM4 + next GEMM1/2 ~1800cy.
        half8 fA01_n[2][2];
        load_feat2(feat16, node_feat, use_f16, ndr_n[0], ndr_n[1], q, fA01_n);

        // ---- GEMM4: relu + Wm2 dot + 4-step butterfly + store ----
        #pragma unroll
        for (int rt = 0; rt < 4; ++rt) {
            #pragma unroll
            for (int r = 0; r < 4; ++r) {
                float p = 0.0f;
                #pragma unroll
                for (int ct = 0; ct < 4; ++ct)
                    p = fmaf(fmaxf(acc[rt][ct][r], 0.0f), wm2v[ct], p);
                p += __shfl_xor(p, 1);
                p += __shfl_xor(p, 2);
                p += __shfl_xor(p, 4);
                p += __shfl_xor(p, 8);
                if (ln == 0)
                    out[base + r0 + rt * 16 + q * 4 + r] = p + bm2s;
            }
        }

        // ---- rotate pipeline state ----
        base = nbase;
        #pragma unroll
        for (int rt = 0; rt < 4; ++rt)
            ndr[rt] = ndr_n[rt];
        kkc = kk_n;
        enc = enc_n;
        #pragma unroll
        for (int rr = 0; rr < 2; ++rr)
            #pragma unroll
            for (int kt = 0; kt < 2; ++kt)
                fA01[rr][kt] = fA01_n[rr][kt];
    }
}

extern "C" void kernel_launch(void* const* d_in, const int* in_sizes, int n_in,
                              void* d_out, int out_size, void* d_ws, size_t ws_size,
                              hipStream_t stream) {
    const float* pos_table = (const float*)d_in[0];
    const float* node_feat = (const float*)d_in[1];
    const float* W1        = (const float*)d_in[2];
    const float* b1        = (const float*)d_in[3];
    const float* W2        = (const float*)d_in[4];
    const float* b2        = (const float*)d_in[5];
    const float* Wm1       = (const float*)d_in[6];
    const float* bm1       = (const float*)d_in[7];
    const float* Wm2       = (const float*)d_in[8];
    const float* bm2       = (const float*)d_in[9];
    const int*   key_idx   = (const int*)d_in[10];
    const int*   node_idx  = (const int*)d_in[11];
    float* out = (float*)d_out;

    const int rows  = in_sizes[10];                // 1,048,576
    const int nfeat = in_sizes[1];                 // NUM_NODES*64

    _Float16* feat16 = (_Float16*)d_ws;
    const size_t need = (size_t)nfeat * sizeof(_Float16);
    const int use_f16 = (ws_size >= need) ? 1 : 0;

    if (use_f16) {
        const int n8 = nfeat / 8;
        feat_to_f16<<<(n8 + 255) / 256, 256, 0, stream>>>(node_feat, feat16, n8);
    }

    neurtw_r17<<<GRID_MAIN, 256, 0, stream>>>(
        pos_table, node_feat, W1, b1, W2, b2, Wm1, bm1, Wm2, bm2,
        key_idx, node_idx, feat16, use_f16, out, rows);
}